// Round 1
// baseline (391.335 us; speedup 1.0000x reference)
//
#include <hip/hip_runtime.h>

#define HW_   (512 * 512)   // pixels per image
#define NIMG  8
#define NC    19            // classes
#define NSP   2048          // superpixels per image
#define TC    20            // target row stride (C+1, last col sliced off)

// ---------------------------------------------------------------------------
// Kernel 1: detect spmask element width + zero the accumulators.
// jax bool may arrive as 1-byte bools or widened to int32/float32.
//  - packed bool bytes: every byte in {0,1} -> word & 0xFEFEFEFE == 0, and
//    (with overwhelming probability over 1024 words) some word has bits above
//    the low byte.
//  - int32 0/1: word & 0xFFFFFF00 == 0 always.
//  - float32 0.0/1.0: 1.0f = 0x3F800000 -> trips 0xFEFEFEFE, and "word != 0"
//    is the correct truth test anyway (collapses into the int32 path).
// flag = 1 -> 4-byte elements (test word != 0); flag = 0 -> 1-byte elements.
// ---------------------------------------------------------------------------
__global__ void det_init(const unsigned int* __restrict__ spm,
                         float* __restrict__ loss,
                         unsigned int* __restrict__ cnt,
                         unsigned int* __restrict__ flag) {
    unsigned int lane = threadIdx.x;   // 64 threads
    unsigned int nonlow = 0, upper = 0;
    for (int i = lane; i < 1024; i += 64) {
        unsigned int v = spm[i];
        nonlow |= (v & 0xFEFEFEFEu);
        upper  |= (v & 0xFFFFFF00u);
    }
    unsigned long long b1 = __ballot(nonlow != 0);
    unsigned long long b2 = __ballot(upper != 0);
    if (lane == 0) {
        bool bytes = (b1 == 0ull) && (b2 != 0ull);
        *flag = bytes ? 0u : 1u;
        *loss = 0.0f;
        *cnt  = 0u;
    }
}

// ---------------------------------------------------------------------------
// Kernel 2: fused softmax + target gather + masked NLL reduction.
// One thread handles 4 consecutive pixels (float4 loads per class -> fully
// coalesced 1 KiB/wave/class). 19-class column kept in registers (76 VGPR).
// ---------------------------------------------------------------------------
__global__ __launch_bounds__(256) void mcce_main(
    const float* __restrict__ x,      // (N, C, H*W)
    const float* __restrict__ tgt,    // (N, NSP, TC)
    const int*   __restrict__ sp,     // (N, H*W)
    const void*  __restrict__ spm,    // (N, H*W) bool (1B or 4B)
    float* __restrict__ loss,
    unsigned int* __restrict__ cnt,
    const unsigned int* __restrict__ flag) {

    int tid = blockIdx.x * blockDim.x + threadIdx.x;  // one per 4 pixels
    int n = tid >> 16;                 // HW/4 = 65536 quads per image
    int p = (tid & 65535) << 2;        // base pixel within image
    size_t gp = (size_t)n * HW_ + p;   // global pixel index (multiple of 4)

    // Load 19-class logit column for 4 pixels into registers.
    float lv[NC][4];
    const float* b = x + (size_t)n * NC * HW_ + p;
#pragma unroll
    for (int c = 0; c < NC; ++c) {
        float4 v = *(const float4*)(b + (size_t)c * HW_);
        lv[c][0] = v.x; lv[c][1] = v.y; lv[c][2] = v.z; lv[c][3] = v.w;
    }

    // Per-pixel max over classes.
    float mx[4];
#pragma unroll
    for (int j = 0; j < 4; ++j) mx[j] = lv[0][j];
#pragma unroll
    for (int c = 1; c < NC; ++c)
#pragma unroll
        for (int j = 0; j < 4; ++j) mx[j] = fmaxf(mx[j], lv[c][j]);

    // Superpixel indices -> target rows (160 KB/image, L1/L2 resident).
    int4 s4 = *(const int4*)(sp + gp);
    const float* trow[4];
    trow[0] = tgt + ((size_t)n * NSP + s4.x) * TC;
    trow[1] = tgt + ((size_t)n * NSP + s4.y) * TC;
    trow[2] = tgt + ((size_t)n * NSP + s4.z) * TC;
    trow[3] = tgt + ((size_t)n * NSP + s4.w) * TC;

    // exp-sum, target-weighted exp-sum, target-any-hot.
    float se[4] = {0, 0, 0, 0}, ts[4] = {0, 0, 0, 0}, th[4] = {0, 0, 0, 0};
#pragma unroll
    for (int c = 0; c < NC; ++c) {
#pragma unroll
        for (int j = 0; j < 4; ++j) {
            float e = __expf(lv[c][j] - mx[j]);
            float t = trow[j][c];           // exact 0.0f / 1.0f
            se[j] += e;
            ts[j] = fmaf(t, e, ts[j]);
            th[j] += t;
        }
    }

    // Mask load, width per detected flag (wave-uniform branch).
    int mk[4];
    if (*flag) {
        int4 m = *(const int4*)((const int*)spm + gp);
        mk[0] = m.x; mk[1] = m.y; mk[2] = m.z; mk[3] = m.w;
    } else {
        uchar4 m = *(const uchar4*)((const unsigned char*)spm + gp);
        mk[0] = m.x; mk[1] = m.y; mk[2] = m.z; mk[3] = m.w;
    }

    float lsum = 0.0f;
    unsigned int lcnt = 0;
#pragma unroll
    for (int j = 0; j < 4; ++j) {
        bool valid = (mk[j] != 0) && (th[j] > 0.0f);
        if (valid) {
            lsum -= __logf(ts[j] / se[j] + 1e-8f);
            lcnt += 1;
        }
    }

    // Wave-64 shuffle reduction -> one atomic pair per wave.
    for (int o = 32; o > 0; o >>= 1) {
        lsum += __shfl_down(lsum, o);
        lcnt += __shfl_down(lcnt, o);
    }
    if ((threadIdx.x & 63) == 0) {
        atomicAdd(loss, lsum);
        atomicAdd(cnt, lcnt);
    }
}

// ---------------------------------------------------------------------------
// Kernel 3: finalize scalar.
// ---------------------------------------------------------------------------
__global__ void fin(const float* __restrict__ loss,
                    const unsigned int* __restrict__ cnt,
                    float* __restrict__ out) {
    if (threadIdx.x == 0 && blockIdx.x == 0)
        out[0] = *loss / (float)(1u + *cnt);
}

extern "C" void kernel_launch(void* const* d_in, const int* in_sizes, int n_in,
                              void* d_out, int out_size, void* d_ws, size_t ws_size,
                              hipStream_t stream) {
    const float* x   = (const float*)d_in[0];   // inputs (8,19,512,512) f32
    const float* tgt = (const float*)d_in[1];   // targets (8,2048,20) f32
    const int*   sp  = (const int*)d_in[2];     // superpixels (8,512,512) i32
    const void*  spm = d_in[3];                 // spmasks (8,512,512) bool (width detected)

    float*        loss = (float*)d_ws;
    unsigned int* cnt  = (unsigned int*)((char*)d_ws + 4);
    unsigned int* flag = (unsigned int*)((char*)d_ws + 8);

    det_init<<<1, 64, 0, stream>>>((const unsigned int*)spm, loss, cnt, flag);

    int total_quads = NIMG * (HW_ / 4);         // 524288 threads
    mcce_main<<<total_quads / 256, 256, 0, stream>>>(x, tgt, sp, spm, loss, cnt, flag);

    fin<<<1, 64, 0, stream>>>(loss, cnt, (float*)d_out);
}